// Round 7
// baseline (493.745 us; speedup 1.0000x reference)
//
#include <hip/hip_runtime.h>
#include <math.h>
#include <type_traits>

// MS-SSIM loss, 5 levels, 11-tap separable Gaussian (sigma=1.5), VALID padding.
// Round 7: row-streaming kernel with
//  - interleaved {a,b} float2 LDS rows (b64 tap reads: half the DS instrs)
//  - circular 12-deep v-conv ring, 6 compile-time phases (zero shift movs)
//  - paired float2 math throughout (v_pk_fma candidates)
//  - rescaled emit algebra (no 0.5 factors; 2*C1 / 2*C2), exact
// 4-map transform (a=x+y, b=x-y -> P,Q,U,V) as rounds 4-6 (exact).

#define RW 272          // staged cols per row: 256 band + 10 halo + pad

struct GWin { float w[11]; };

__device__ __forceinline__ void f2fma(float w, const float2 v, float2& acc) {
    acc.x = fmaf(w, v.x, acc.x);
    acc.y = fmaf(w, v.y, acc.y);
}
__device__ __forceinline__ void f2sqfma(float w, const float2 v, float2& acc) {
    acc.x = fmaf(w * v.x, v.x, acc.x);
    acc.y = fmaf(w * v.y, v.y, acc.y);
}

template<int RPS>
__global__ __launch_bounds__(256)
void ssim_rows_kernel(const float* __restrict__ X, const float* __restrict__ Y,
                      float* __restrict__ poolX, float* __restrict__ poolY,
                      float* __restrict__ accum,   // [0..95]=ssim, [96..191]=cs
                      int S, int outS, int doPool, GWin gw)
{
    constexpr int NIT = RPS / 2 + 5;     // iterations, 2 input rows each
    __shared__ float2 ab[2][2][RW];      // [slot][row01][col] = {a, b}
    __shared__ float rs[4], rc[4];

    const int ch  = blockIdx.z;
    const int oy0 = blockIdx.x * RPS;
    const int cb0 = blockIdx.y * 256;
    const int tid = threadIdx.x;
    const int halfS = S >> 1;

    const float* Xc = X + (size_t)ch * S * S;
    const float* Yc = Y + (size_t)ch * S * S;

    // staging task decode: 272 float2-col tasks over 2 rows (136 per row)
    const int  r0_ = (tid < 136) ? 0 : 1;
    const int  c20 = (tid < 136) ? tid : tid - 136;
    const bool hasT1 = (tid < 16);
    const int  c21 = 120 + tid;          // extra task: row 1, c2 in [120,136)

    float2 sx0, sy0, sx1, sy1;           // prefetched global data

    auto issue = [&](int baseRow) {
        {
            int gr = baseRow + r0_; if (gr > S - 1) gr = S - 1;
            const float* xr = Xc + (size_t)gr * S;
            const float* yr = Yc + (size_t)gr * S;
            int gc = cb0 + 2 * c20;
            if (gc + 1 < S) {
                sx0 = *reinterpret_cast<const float2*>(xr + gc);
                sy0 = *reinterpret_cast<const float2*>(yr + gc);
            } else {
                int g0 = gc < S ? gc : S - 1;
                sx0.x = xr[g0]; sx0.y = xr[S - 1];
                sy0.x = yr[g0]; sy0.y = yr[S - 1];
            }
        }
        if (hasT1) {
            int gr = baseRow + 1; if (gr > S - 1) gr = S - 1;
            const float* xr = Xc + (size_t)gr * S;
            const float* yr = Yc + (size_t)gr * S;
            int gc = cb0 + 2 * c21;
            if (gc + 1 < S) {
                sx1 = *reinterpret_cast<const float2*>(xr + gc);
                sy1 = *reinterpret_cast<const float2*>(yr + gc);
            } else {
                int g0 = gc < S ? gc : S - 1;
                sx1.x = xr[g0]; sx1.y = xr[S - 1];
                sy1.x = yr[g0]; sy1.y = yr[S - 1];
            }
        }
    };
    auto write_slot = [&](int sl) {      // interleaved {a,b}: one b128 per task
        float4 v0;
        v0.x = sx0.x + sy0.x; v0.y = sx0.x - sy0.x;
        v0.z = sx0.y + sy0.y; v0.w = sx0.y - sy0.y;
        *reinterpret_cast<float4*>(&ab[sl][r0_][2 * c20]) = v0;
        if (hasT1) {
            float4 v1;
            v1.x = sx1.x + sy1.x; v1.y = sx1.x - sy1.x;
            v1.z = sx1.y + sy1.y; v1.w = sx1.y - sy1.y;
            *reinterpret_cast<float4*>(&ab[sl][1][2 * c21]) = v1;
        }
    };

    // circular pending ring: 12 slots x {P,Q} + {U,V}
    float2 pendPQ[12], pendUV[12];
    #pragma unroll
    for (int i = 0; i < 12; ++i) { pendPQ[i] = make_float2(0.f, 0.f); pendUV[i] = make_float2(0.f, 0.f); }

    float ssum = 0.f, csum = 0.f;
    const float C1x2 = 2e-4f, C2x2 = 1.8e-3f;
    const bool colOK = (cb0 + tid) < outS;

    auto emitrow = [&](const float2 PQ, const float2 UV, int orow) {
        float p2 = PQ.x * PQ.x, q2 = PQ.y * PQ.y;
        float A = p2 - q2;                         // 2*(2 mu12)
        float csn = (UV.x - UV.y - A) + C2x2;      // 2*(2 sigma12) + 2C2
        float csd = (UV.x + UV.y - p2 - q2) + C2x2;
        float cs  = csn * __builtin_amdgcn_rcpf(csd);
        float ss  = (A + C1x2) * __builtin_amdgcn_rcpf(p2 + q2 + C1x2) * cs;
        if (orow < outS && colOK) { ssum += ss; csum += cs; }
    };

    // prologue
    issue(oy0);
    write_slot(0);
    issue(oy0 + 2);
    __syncthreads();

    auto body = [&](auto Pc, auto Ec, int k) {
        constexpr int  P    = decltype(Pc)::value;
        constexpr bool EMIT = decltype(Ec)::value;
        const int sl = k & 1;
        if (k + 1 < NIT) {
            write_slot(sl ^ 1);                  // rows 2(k+1), 2(k+1)+1
            if (k + 3 <= NIT) issue(oy0 + 2 * (k + 2));
        }

        // h-conv for the 2 staged rows (b64 taps, paired math)
        float2 hPQ0 = make_float2(0.f, 0.f), hUV0 = make_float2(0.f, 0.f);
        float2 hPQ1 = make_float2(0.f, 0.f), hUV1 = make_float2(0.f, 0.f);
        #pragma unroll
        for (int t = 0; t < 11; ++t) {
            float w = gw.w[t];
            float2 v = ab[sl][0][tid + t];
            f2fma(w, v, hPQ0); f2sqfma(w, v, hUV0);
        }
        #pragma unroll
        for (int t = 0; t < 11; ++t) {
            float w = gw.w[t];
            float2 v = ab[sl][1][tid + t];
            f2fma(w, v, hPQ1); f2sqfma(w, v, hUV1);
        }

        // v-accumulate into the circular ring (all indices compile-time)
        constexpr int base = (2 * P + 2) % 12;
        #pragma unroll
        for (int j = 0; j <= 10; ++j) {
            int s = (base + j) % 12;
            float w = gw.w[10 - j];
            f2fma(w, hPQ0, pendPQ[s]); f2fma(w, hUV0, pendUV[s]);
        }
        #pragma unroll
        for (int j = 0; j <= 10; ++j) {
            int s = (base + 1 + j) % 12;
            float w = gw.w[10 - j];
            f2fma(w, hPQ1, pendPQ[s]); f2fma(w, hUV1, pendUV[s]);
        }

        // retire slots base, base+1 (outputs 2k-10, 2k-9)
        constexpr int b1 = (base + 1) % 12;
        if (EMIT) {
            emitrow(pendPQ[base], pendUV[base], oy0 + 2 * k - 10);
            emitrow(pendPQ[b1],   pendUV[b1],   oy0 + 2 * k - 9);
        }
        pendPQ[base] = make_float2(0.f, 0.f); pendUV[base] = make_float2(0.f, 0.f);
        pendPQ[b1]   = make_float2(0.f, 0.f); pendUV[b1]   = make_float2(0.f, 0.f);

        // 2x2 pool of the staged rows
        if (doPool && tid < 128 && k < (RPS >> 1)) {
            float4 q0 = *reinterpret_cast<const float4*>(&ab[sl][0][2 * tid]);
            float4 q1 = *reinterpret_cast<const float4*>(&ab[sl][1][2 * tid]);
            float sa = q0.x + q0.z + q1.x + q1.z;
            float sb = q0.y + q0.w + q1.y + q1.w;
            int pc = (cb0 >> 1) + tid;
            if (pc < halfS) {
                int prow = (oy0 >> 1) + k;
                size_t o = (size_t)ch * halfS * halfS + (size_t)prow * halfS + pc;
                poolX[o] = 0.125f * (sa + sb);
                poolY[o] = 0.125f * (sa - sb);
            }
        }
        __syncthreads();
    };

    #define IC(v) std::integral_constant<int, (v)>{}
    #define BT    std::integral_constant<bool, true>{}
    #define BF    std::integral_constant<bool, false>{}

    // first pass: phases 0..4 warm up (clear retires garbage), phase 5 emits rows 0,1
    body(IC(0), BF, 0); body(IC(1), BF, 1); body(IC(2), BF, 2);
    body(IC(3), BF, 3); body(IC(4), BF, 4); body(IC(5), BT, 5);
    int k = 6;
    for (; k + 6 <= NIT; k += 6) {
        body(IC(0), BT, k);     body(IC(1), BT, k + 1); body(IC(2), BT, k + 2);
        body(IC(3), BT, k + 3); body(IC(4), BT, k + 4); body(IC(5), BT, k + 5);
    }
    if (k     < NIT) body(IC(0), BT, k);
    if (k + 1 < NIT) body(IC(1), BT, k + 1);
    if (k + 2 < NIT) body(IC(2), BT, k + 2);
    if (k + 3 < NIT) body(IC(3), BT, k + 3);
    if (k + 4 < NIT) body(IC(4), BT, k + 4);

    #undef IC
    #undef BT
    #undef BF

    // block reduction + atomic accumulate
    for (int off = 32; off > 0; off >>= 1) {
        ssum += __shfl_down(ssum, off);
        csum += __shfl_down(csum, off);
    }
    int wid = tid >> 6, lane = tid & 63;
    if (lane == 0) { rs[wid] = ssum; rc[wid] = csum; }
    __syncthreads();
    if (tid == 0) {
        float s = rs[0] + rs[1] + rs[2] + rs[3];
        float c = rc[0] + rc[1] + rc[2] + rc[3];
        atomicAdd(&accum[ch], s);
        atomicAdd(&accum[96 + ch], c);
    }
}

__global__ void finalize_kernel(const float* __restrict__ accum, float* __restrict__ out)
{
    __shared__ float red[2];
    const int t = threadIdx.x;   // 128 threads
    const float w[5]   = {0.0448f, 0.2856f, 0.3001f, 0.2363f, 0.1333f};
    const float inv[5] = {1.f / (502.f * 502.f), 1.f / (246.f * 246.f),
                          1.f / (118.f * 118.f), 1.f / (54.f * 54.f),
                          1.f / (22.f * 22.f)};
    float ms = 0.f;
    if (t < 96) {
        ms = 1.f;
        #pragma unroll
        for (int l = 0; l < 5; ++l) {
            float v = (l < 4) ? accum[l * 192 + 96 + t] : accum[l * 192 + t];
            v *= inv[l];
            v = fmaxf(v, 0.f);
            ms *= powf(v, w[l]);
        }
    }
    for (int off = 32; off > 0; off >>= 1) ms += __shfl_down(ms, off);
    int wid = t >> 6, lane = t & 63;
    if (lane == 0) red[wid] = ms;
    __syncthreads();
    if (t == 0) out[0] = 1.f - (red[0] + red[1]) * (1.f / 96.f);
}

extern "C" void kernel_launch(void* const* d_in, const int* in_sizes, int n_in,
                              void* d_out, int out_size, void* d_ws, size_t ws_size,
                              hipStream_t stream)
{
    (void)in_sizes; (void)n_in; (void)out_size; (void)ws_size;
    const float* X = (const float*)d_in[0];
    const float* Y = (const float*)d_in[1];
    float* out = (float*)d_out;
    float* ws  = (float*)d_ws;

    // Gaussian window (size 11, sigma 1.5), normalized
    GWin gw;
    {
        double g[11], s = 0.0;
        for (int i = 0; i < 11; ++i) { double d = i - 5; g[i] = exp(-(d * d) / 4.5); s += g[i]; }
        for (int i = 0; i < 11; ++i) gw.w[i] = (float)(g[i] / s);
    }

    // workspace layout (floats)
    float* accum = ws;                 // 5 levels * 192
    size_t off = 1024;
    float* p1x = ws + off; off += (size_t)96 * 256 * 256;
    float* p1y = ws + off; off += (size_t)96 * 256 * 256;
    float* p2x = ws + off; off += (size_t)96 * 128 * 128;
    float* p2y = ws + off; off += (size_t)96 * 128 * 128;
    float* p3x = ws + off; off += (size_t)96 * 64 * 64;
    float* p3y = ws + off; off += (size_t)96 * 64 * 64;
    float* p4x = ws + off; off += (size_t)96 * 32 * 32;
    float* p4y = ws + off; off += (size_t)96 * 32 * 32;

    hipMemsetAsync(accum, 0, 5 * 192 * sizeof(float), stream);

    ssim_rows_kernel<64><<<dim3(8, 2, 96), 256, 0, stream>>>(X,   Y,   p1x, p1y, accum + 0,   512, 502, 1, gw);
    ssim_rows_kernel<64><<<dim3(4, 1, 96), 256, 0, stream>>>(p1x, p1y, p2x, p2y, accum + 192, 256, 246, 1, gw);
    ssim_rows_kernel<32><<<dim3(4, 1, 96), 256, 0, stream>>>(p2x, p2y, p3x, p3y, accum + 384, 128, 118, 1, gw);
    ssim_rows_kernel<32><<<dim3(2, 1, 96), 256, 0, stream>>>(p3x, p3y, p4x, p4y, accum + 576, 64,  54,  1, gw);
    ssim_rows_kernel<32><<<dim3(1, 1, 96), 256, 0, stream>>>(p4x, p4y, nullptr, nullptr, accum + 768, 32, 22, 0, gw);

    finalize_kernel<<<1, 128, 0, stream>>>(accum, out);
}

// Round 8
// 218.018 us; speedup vs baseline: 2.2647x; 2.2647x over previous
//
#include <hip/hip_runtime.h>
#include <math.h>

// MS-SSIM loss, 5 levels, 11-tap separable Gaussian (sigma=1.5), VALID padding.
// Round 8: round-6 row-streaming structure (runtime loop, shift ring, low VGPR)
// + round-7-verified DS reduction: interleaved {a,b} float2 LDS rows so each
// h-conv tap is ONE ds_read_b64 (22/iter instead of 44 ds_read_b32), float2-
// packed pending ring, x2-rescaled emit algebra (exact).
// 4-map transform (a=x+y, b=x-y -> P,Q,U,V) as rounds 4-7 (exact).

#define RW 272          // staged cols per row: 256 band + 10 halo + pad

struct GWin { float w[11]; };

__global__ __launch_bounds__(256)
void ssim_rows_kernel(const float* __restrict__ X, const float* __restrict__ Y,
                      float* __restrict__ poolX, float* __restrict__ poolY,
                      float* __restrict__ accum,   // [0..95]=ssim, [96..191]=cs
                      int S, int outS, int doPool, int rps, GWin gw)
{
    __shared__ float2 ab[2][2][RW];      // [slot][row01][col] = {a, b}
    __shared__ float rs[4], rc[4];

    const int ch  = blockIdx.z;
    const int oy0 = blockIdx.x * rps;
    const int cb0 = blockIdx.y * 256;
    const int tid = threadIdx.x;
    const int halfS = S >> 1;
    const int NIT = (rps + 10) >> 1;     // iterations (2 input rows each)

    const float* Xc = X + (size_t)ch * S * S;
    const float* Yc = Y + (size_t)ch * S * S;

    // staging task decode: 272 float2-col tasks over 2 rows (136 per row)
    const int  r0_ = (tid < 136) ? 0 : 1;
    const int  c20 = (tid < 136) ? tid : tid - 136;
    const bool hasT1 = (tid < 16);
    const int  c21 = 120 + tid;          // extra task: row 1, c2 in [120,136)

    float2 sx0, sy0, sx1, sy1;           // prefetched global data

    auto issue = [&](int baseRow) {      // load rows baseRow, baseRow+1 -> regs
        {
            int gr = baseRow + r0_; if (gr > S - 1) gr = S - 1;
            const float* xr = Xc + (size_t)gr * S;
            const float* yr = Yc + (size_t)gr * S;
            int gc = cb0 + 2 * c20;
            if (gc + 1 < S) {
                sx0 = *reinterpret_cast<const float2*>(xr + gc);
                sy0 = *reinterpret_cast<const float2*>(yr + gc);
            } else {
                int g0 = gc < S ? gc : S - 1;
                sx0.x = xr[g0]; sx0.y = xr[S - 1];
                sy0.x = yr[g0]; sy0.y = yr[S - 1];
            }
        }
        if (hasT1) {
            int gr = baseRow + 1; if (gr > S - 1) gr = S - 1;
            const float* xr = Xc + (size_t)gr * S;
            const float* yr = Yc + (size_t)gr * S;
            int gc = cb0 + 2 * c21;
            if (gc + 1 < S) {
                sx1 = *reinterpret_cast<const float2*>(xr + gc);
                sy1 = *reinterpret_cast<const float2*>(yr + gc);
            } else {
                int g0 = gc < S ? gc : S - 1;
                sx1.x = xr[g0]; sx1.y = xr[S - 1];
                sy1.x = yr[g0]; sy1.y = yr[S - 1];
            }
        }
    };
    auto write_slot = [&](int sl) {      // regs -> LDS interleaved {a,b}: one b128 per task
        float4 v0;
        v0.x = sx0.x + sy0.x; v0.y = sx0.x - sy0.x;
        v0.z = sx0.y + sy0.y; v0.w = sx0.y - sy0.y;
        *reinterpret_cast<float4*>(&ab[sl][r0_][2 * c20]) = v0;
        if (hasT1) {
            float4 v1;
            v1.x = sx1.x + sy1.x; v1.y = sx1.x - sy1.x;
            v1.z = sx1.y + sy1.y; v1.w = sx1.y - sy1.y;
            *reinterpret_cast<float4*>(&ab[sl][1][2 * c21]) = v1;
        }
    };

    // pending v-conv partials: 12 slots x {P,Q} + {U,V}, float2-packed
    float2 pendPQ[12], pendUV[12];
    #pragma unroll
    for (int i = 0; i < 12; ++i) { pendPQ[i] = make_float2(0.f, 0.f); pendUV[i] = make_float2(0.f, 0.f); }

    float ssum = 0.f, csum = 0.f;
    const float C1x2 = 2e-4f, C2x2 = 1.8e-3f;
    const bool colOK = (cb0 + tid) < outS;

    // prologue
    issue(oy0);
    write_slot(0);
    issue(oy0 + 2);
    __syncthreads();

    for (int k = 0; k < NIT; ++k) {
        const int sl = k & 1;
        if (k + 1 < NIT) {
            write_slot(sl ^ 1);          // rows oy0+2(k+1) (regs from iter k-1)
            if (k + 3 <= NIT) issue(oy0 + 2 * (k + 2));
        }

        // ---- h-conv for the 2 staged rows: one b64 read per tap ----
        float2 hPQ0 = make_float2(0.f, 0.f), hUV0 = make_float2(0.f, 0.f);
        float2 hPQ1 = make_float2(0.f, 0.f), hUV1 = make_float2(0.f, 0.f);
        #pragma unroll
        for (int t = 0; t < 11; ++t) {
            float w = gw.w[t];
            float2 v = ab[sl][0][tid + t];
            hPQ0.x = fmaf(w, v.x, hPQ0.x);
            hPQ0.y = fmaf(w, v.y, hPQ0.y);
            hUV0.x = fmaf(w * v.x, v.x, hUV0.x);
            hUV0.y = fmaf(w * v.y, v.y, hUV0.y);
        }
        #pragma unroll
        for (int t = 0; t < 11; ++t) {
            float w = gw.w[t];
            float2 v = ab[sl][1][tid + t];
            hPQ1.x = fmaf(w, v.x, hPQ1.x);
            hPQ1.y = fmaf(w, v.y, hPQ1.y);
            hUV1.x = fmaf(w * v.x, v.x, hUV1.x);
            hUV1.y = fmaf(w * v.y, v.y, hUV1.y);
        }

        // ---- v-accumulate into pending ring ----
        #pragma unroll
        for (int j = 0; j <= 10; ++j) {          // row r contributes w[10-j] -> slot j
            float w = gw.w[10 - j];
            pendPQ[j].x = fmaf(w, hPQ0.x, pendPQ[j].x);
            pendPQ[j].y = fmaf(w, hPQ0.y, pendPQ[j].y);
            pendUV[j].x = fmaf(w, hUV0.x, pendUV[j].x);
            pendUV[j].y = fmaf(w, hUV0.y, pendUV[j].y);
        }
        #pragma unroll
        for (int j = 1; j <= 11; ++j) {          // row r+1 contributes w[11-j] -> slot j
            float w = gw.w[11 - j];
            pendPQ[j].x = fmaf(w, hPQ1.x, pendPQ[j].x);
            pendPQ[j].y = fmaf(w, hPQ1.y, pendPQ[j].y);
            pendUV[j].x = fmaf(w, hUV1.x, pendUV[j].x);
            pendUV[j].y = fmaf(w, hUV1.y, pendUV[j].y);
        }

        // ---- emit 2 finished output rows (x2-rescaled algebra, exact) ----
        if (k >= 5) {
            #pragma unroll
            for (int e = 0; e < 2; ++e) {
                int orow = oy0 + 2 * k - 10 + e;
                float p = pendPQ[e].x, q = pendPQ[e].y;
                float u = pendUV[e].x, v = pendUV[e].y;
                float p2 = p * p, q2 = q * q;
                float A = p2 - q2;                         // 2*(2 mu12)
                float csn = (u - v - A) + C2x2;            // 2*(2 sigma12) + 2C2
                float csd = (u + v - p2 - q2) + C2x2;
                float cs  = csn * __builtin_amdgcn_rcpf(csd);
                float ss  = (A + C1x2) * __builtin_amdgcn_rcpf(p2 + q2 + C1x2) * cs;
                if (orow < outS && colOK) { ssum += ss; csum += cs; }
            }
        }

        // ---- shift ring by 2 slots ----
        #pragma unroll
        for (int j = 0; j < 10; ++j) { pendPQ[j] = pendPQ[j + 2]; pendUV[j] = pendUV[j + 2]; }
        pendPQ[10] = make_float2(0.f, 0.f); pendUV[10] = make_float2(0.f, 0.f);
        pendPQ[11] = make_float2(0.f, 0.f); pendUV[11] = make_float2(0.f, 0.f);

        // ---- 2x2 pool of the 2 staged rows ----
        if (doPool && tid < 128 && k < (rps >> 1)) {
            float4 q0 = *reinterpret_cast<const float4*>(&ab[sl][0][2 * tid]);
            float4 q1 = *reinterpret_cast<const float4*>(&ab[sl][1][2 * tid]);
            float sa = q0.x + q0.z + q1.x + q1.z;
            float sb = q0.y + q0.w + q1.y + q1.w;
            int pc = (cb0 >> 1) + tid;
            if (pc < halfS) {
                int prow = (oy0 >> 1) + k;
                size_t o = (size_t)ch * halfS * halfS + (size_t)prow * halfS + pc;
                poolX[o] = 0.125f * (sa + sb);
                poolY[o] = 0.125f * (sa - sb);
            }
        }

        __syncthreads();
    }

    // ---- block reduction + atomic accumulate ----
    for (int off = 32; off > 0; off >>= 1) {
        ssum += __shfl_down(ssum, off);
        csum += __shfl_down(csum, off);
    }
    int wid = tid >> 6, lane = tid & 63;
    if (lane == 0) { rs[wid] = ssum; rc[wid] = csum; }
    __syncthreads();
    if (tid == 0) {
        float s = rs[0] + rs[1] + rs[2] + rs[3];
        float c = rc[0] + rc[1] + rc[2] + rc[3];
        atomicAdd(&accum[ch], s);
        atomicAdd(&accum[96 + ch], c);
    }
}

__global__ void finalize_kernel(const float* __restrict__ accum, float* __restrict__ out)
{
    __shared__ float red[2];
    const int t = threadIdx.x;   // 128 threads
    const float w[5]   = {0.0448f, 0.2856f, 0.3001f, 0.2363f, 0.1333f};
    const float inv[5] = {1.f / (502.f * 502.f), 1.f / (246.f * 246.f),
                          1.f / (118.f * 118.f), 1.f / (54.f * 54.f),
                          1.f / (22.f * 22.f)};
    float ms = 0.f;
    if (t < 96) {
        ms = 1.f;
        #pragma unroll
        for (int l = 0; l < 5; ++l) {
            float v = (l < 4) ? accum[l * 192 + 96 + t] : accum[l * 192 + t];
            v *= inv[l];
            v = fmaxf(v, 0.f);
            ms *= powf(v, w[l]);
        }
    }
    for (int off = 32; off > 0; off >>= 1) ms += __shfl_down(ms, off);
    int wid = t >> 6, lane = t & 63;
    if (lane == 0) red[wid] = ms;
    __syncthreads();
    if (t == 0) out[0] = 1.f - (red[0] + red[1]) * (1.f / 96.f);
}

extern "C" void kernel_launch(void* const* d_in, const int* in_sizes, int n_in,
                              void* d_out, int out_size, void* d_ws, size_t ws_size,
                              hipStream_t stream)
{
    (void)in_sizes; (void)n_in; (void)out_size; (void)ws_size;
    const float* X = (const float*)d_in[0];
    const float* Y = (const float*)d_in[1];
    float* out = (float*)d_out;
    float* ws  = (float*)d_ws;

    // Gaussian window (size 11, sigma 1.5), normalized
    GWin gw;
    {
        double g[11], s = 0.0;
        for (int i = 0; i < 11; ++i) { double d = i - 5; g[i] = exp(-(d * d) / 4.5); s += g[i]; }
        for (int i = 0; i < 11; ++i) gw.w[i] = (float)(g[i] / s);
    }

    // workspace layout (floats)
    float* accum = ws;                 // 5 levels * 192
    size_t off = 1024;
    float* p1x = ws + off; off += (size_t)96 * 256 * 256;
    float* p1y = ws + off; off += (size_t)96 * 256 * 256;
    float* p2x = ws + off; off += (size_t)96 * 128 * 128;
    float* p2y = ws + off; off += (size_t)96 * 128 * 128;
    float* p3x = ws + off; off += (size_t)96 * 64 * 64;
    float* p3y = ws + off; off += (size_t)96 * 64 * 64;
    float* p4x = ws + off; off += (size_t)96 * 32 * 32;
    float* p4y = ws + off; off += (size_t)96 * 32 * 32;

    hipMemsetAsync(accum, 0, 5 * 192 * sizeof(float), stream);

    auto launch = [&](const float* x, const float* y, float* px_, float* py_,
                      float* acc, int S, int outS, int pool) {
        int rps = (S >= 512) ? 64 : 32;               // output rows per block
        dim3 g((S + rps - 1) / rps, (S + 255) / 256, 96);
        ssim_rows_kernel<<<g, 256, 0, stream>>>(x, y, px_, py_, acc, S, outS, pool, rps, gw);
    };

    launch(X,   Y,   p1x, p1y, accum + 0,   512, 502, 1);
    launch(p1x, p1y, p2x, p2y, accum + 192, 256, 246, 1);
    launch(p2x, p2y, p3x, p3y, accum + 384, 128, 118, 1);
    launch(p3x, p3y, p4x, p4y, accum + 576, 64,  54,  1);
    launch(p4x, p4y, nullptr, nullptr, accum + 768, 32, 22, 0);

    finalize_kernel<<<1, 128, 0, stream>>>(accum, out);
}